// Round 7
// baseline (273.259 us; speedup 1.0000x reference)
//
#include <hip/hip_runtime.h>

#define N_E   1024
#define EDIM  256
#define BB    16
#define TT    1024
#define NROW  (BB*TT)        /* 16384 */
#define NCOL  1025
#define NPAD  1152           /* 9*128 */
#define PERS  (0.1f/1024.0f)
#define EPSC  (1e-6f/1024.0f)

/* d_out layout (float32): z_q [0,4194304) | loss 4194304 | ind [4194305,+16384) | v 4210689 */
#define OUT_LOSS 4194304
#define OUT_IDX  4194305
#define OUT_V    4210689

/* ws layout (bytes) */
#define WS_ZB   0ull                               /* 16384*256*2  = 8388608  */
#define WS_BBF  8388608ull                         /* 1152*256*2   = 589824   */
#define WS_BSQ  8978432ull                         /* 1152*4       = 4608     */
#define WS_E    8983552ull                         /* 16384*1152*4 = 75497472 */
#define WS_IND  84481024ull                        /* 16384*4                 */
#define WS_PART 84546560ull                        /* 16384*4                 */

typedef __attribute__((ext_vector_type(8))) short short8;
typedef __attribute__((ext_vector_type(4))) float floatx4;

__device__ __forceinline__ unsigned short f2bf(float f) {
    unsigned int u = __float_as_uint(f);
    u = (u + 0x7fffu + ((u >> 16) & 1u)) >> 16;   /* RNE */
    return (unsigned short)u;
}

/* ---------------- K0: convert z/book -> bf16, compute bsq (fp32) ---------------- */
__global__ __launch_bounds__(256) void k0_prep(const float* __restrict__ z,
                                               const float* __restrict__ book,
                                               unsigned short* __restrict__ zb,
                                               unsigned short* __restrict__ bb,
                                               float* __restrict__ bsq) {
    int bx = blockIdx.x, tid = threadIdx.x;
    if (bx < 4096) {                     /* z: 4096 blocks * 256 thr * 4 floats */
        float4 v = ((const float4*)z)[bx * 256 + tid];
        size_t o = ((size_t)bx * 256 + tid) * 4;
        zb[o + 0] = f2bf(v.x); zb[o + 1] = f2bf(v.y);
        zb[o + 2] = f2bf(v.z); zb[o + 3] = f2bf(v.w);
    } else {                             /* book rows, padded to 1152 with zeros */
        int row = bx - 4096;             /* 0..1151 */
        float v = (row < NCOL) ? book[(size_t)row * EDIM + tid] : 0.0f;
        bb[(size_t)row * EDIM + tid] = f2bf(v);
        __shared__ float sd[256];
        sd[tid] = v * v;
        __syncthreads();
        for (int s = 128; s > 0; s >>= 1) { if (tid < s) sd[tid] += sd[tid + s]; __syncthreads(); }
        if (tid == 0) bsq[row] = sd[0];
    }
}

/* ---------------- K1: e[r][n] = bsq[n] - 2 * dot(z[r], book[n])  (bf16 MFMA) ---- */
__global__ __launch_bounds__(256) void k1_gemm(const unsigned short* __restrict__ zb,
                                               const unsigned short* __restrict__ bb,
                                               const float* __restrict__ bsq,
                                               float* __restrict__ e) {
    int tid = threadIdx.x;
    int lane = tid & 63, w = tid >> 6;
    int mBase = blockIdx.x * 128 + (w >> 1) * 64;
    int nBase = blockIdx.y * 128 + (w & 1) * 64;
    int r = lane & 15, q = lane >> 4;

    floatx4 acc[4][4];
    #pragma unroll
    for (int i = 0; i < 4; i++)
        #pragma unroll
        for (int j = 0; j < 4; j++) acc[i][j] = (floatx4){0.f, 0.f, 0.f, 0.f};

    const short8* A = (const short8*)zb;   /* row stride 256 bf16 = 32 short8 */
    const short8* Bm = (const short8*)bb;

    #pragma unroll
    for (int ks = 0; ks < 8; ks++) {
        int k8 = ks * 4 + q;               /* short8 index in row: (ks*32+q*8)/8 */
        short8 a[4], b[4];
        #pragma unroll
        for (int i = 0; i < 4; i++) a[i] = A[(size_t)(mBase + i * 16 + r) * 32 + k8];
        #pragma unroll
        for (int j = 0; j < 4; j++) b[j] = Bm[(size_t)(nBase + j * 16 + r) * 32 + k8];
        #pragma unroll
        for (int i = 0; i < 4; i++)
            #pragma unroll
            for (int j = 0; j < 4; j++)
                acc[i][j] = __builtin_amdgcn_mfma_f32_16x16x32_bf16(a[i], b[j], acc[i][j], 0, 0, 0);
    }

    float bsql[4];
    #pragma unroll
    for (int j = 0; j < 4; j++) bsql[j] = bsq[nBase + j * 16 + r];

    #pragma unroll
    for (int i = 0; i < 4; i++)
        #pragma unroll
        for (int rr = 0; rr < 4; rr++) {
            int m = mBase + i * 16 + q * 4 + rr;
            float* erow = e + (size_t)m * NPAD;
            #pragma unroll
            for (int j = 0; j < 4; j++)
                erow[nBase + j * 16 + r] = fmaf(-2.0f, acc[i][j][rr], bsql[j]);
        }
}

/* ---------------- K2: serial neighbor scan, one block per batch row ------------
   Phase A (4 waves): fp32 argmin of d[b,0,:] reference-style.
   Phase B (wave 0): integer-scan with a DEEP DMA ring:
   - 64-col window per row, ONE global_load_lds (4B/lane, zero VGPR cost)
     into a 64-slot LDS ring (slot = t & 63, stride 65 floats: lane l reads
     its (A,B)=(col l, col l+1) pair as adjacent LDS floats -> ds_read2).
   - Chunks of 8 rows, lookahead 5 chunks (40 rows) -> issue-to-consume
     cover ~4 iterations >> HBM latency. Counted wait vmcnt(36).
   vmcnt ledger (verified): per iter issue [8 loads]..wait..[1 store].
   Ops after L(c+1) at iter-c wait = 4 stores + 4x8 loads = 36. Prologue
   [L(k) S]x5 gives identical counts (vmcnt(37) releases chunk 0). Max
   outstanding 45 <= 63. Prologue stores are VOLATILE so dead-store elim
   can't break the ledger.
   Drift bound: rows issued <= 48 ahead of consumption; rel = ind_t - base
   <= 48 (< 63) when base < 960; base clamp min(ind,960) makes col 1023 the
   cap lane (q forced 0 = reference behavior at ind=1023); the unwritten pad
   float at slot+64 is only read by lane 63 and only consumed when capped.  */

#define GCH   8
#define DEP   5
#define SSTR  65                          /* floats per ring slot (64 + pad) */

#define ISS(j) { int _t = ti + j; int _tc = _t < 1024 ? _t : 1023; \
    __builtin_amdgcn_global_load_lds( \
        (const __attribute__((address_space(1))) void*)(pE + (size_t)_tc * NPAD), \
        (__attribute__((address_space(3))) void*)&ring[(_t & 63) * SSTR], 4, 0, 0); }
#define ISSUE8 ISS(0) ISS(1) ISS(2) ISS(3) ISS(4) ISS(5) ISS(6) ISS(7)

#define QC8(j) { int _t = tq + j; int _s = (_t & 63) * SSTR; \
    float _A  = ring[_s + lane]; \
    float _Bv = ring[_s + lane + 1]; \
    int _qv = (int)((_Bv - _A) * QS); \
    q_##j = _capn ? 0 : _qv; }
#define QCOMP8 QC8(0) QC8(1) QC8(2) QC8(3) QC8(4) QC8(5) QC8(6) QC8(7)

#define CH8(j) { int _rel = ind - b0; \
    int _qv = __builtin_amdgcn_readlane(q_##j, _rel); \
    bool _stay = (kk <= _qv); \
    int _ip1 = ind + 1; _ip1 = _ip1 < 1023 ? _ip1 : 1023; \
    ind = _stay ? ind : _ip1; \
    kk  = _stay ? kk + 1 : 0; \
    packed = (lane == j) ? ind : packed; }
#define CHAIN8 CH8(0) CH8(1) CH8(2) CH8(3) CH8(4) CH8(5) CH8(6) CH8(7)

__global__ __launch_bounds__(256, 1) void k2_scan(const float* __restrict__ z,
                                                  const float* __restrict__ book,
                                                  const float* __restrict__ bsq,
                                                  const float* __restrict__ e,
                                                  int* __restrict__ wind) {
    __shared__ float sb[4]; __shared__ int si[4];
    __shared__ float ring[64 * SSTR];    /* 16640 B */

    int b = blockIdx.x, tid = threadIdx.x;
    int lane = tid & 63, w = tid >> 6;

    const float4* zr = (const float4*)(z + (size_t)b * TT * EDIM);  /* t=0 row */
    float4 zv = zr[lane];
    float s = zv.x * zv.x + zv.y * zv.y + zv.z * zv.z + zv.w * zv.w;
    #pragma unroll
    for (int off = 32; off; off >>= 1) s += __shfl_xor(s, off, 64);
    float zsq = s;

    float best = 3.4e38f; int bidx = 0;
    for (int wi = w; wi < 17; wi += 4) {
        int n = wi * 64 + lane;
        if (n < NCOL) {
            const float4* br = (const float4*)(book + (size_t)n * EDIM);
            float c0 = 0.f, c1 = 0.f, c2 = 0.f, c3 = 0.f;
            #pragma unroll 8
            for (int k = 0; k < 64; k++) {
                float4 bo = br[k]; float4 za = zr[k];
                c0 = fmaf(za.x, bo.x, c0); c1 = fmaf(za.y, bo.y, c1);
                c2 = fmaf(za.z, bo.z, c2); c3 = fmaf(za.w, bo.w, c3);
            }
            float cr = (c0 + c1) + (c2 + c3);
            float d0 = (zsq + bsq[n]) - 2.0f * cr;     /* reference-style formation */
            if (d0 < best || (d0 == best && n < bidx)) { best = d0; bidx = n; }
        }
    }
    #pragma unroll
    for (int off = 32; off; off >>= 1) {
        float ob = __shfl_xor(best, off, 64);
        int   oi = __shfl_xor(bidx, off, 64);
        if (ob < best || (ob == best && oi < bidx)) { best = ob; bidx = oi; }
    }
    if (lane == 0) { sb[w] = best; si[w] = bidx; }
    __syncthreads();
    if (w != 0) return;

    best = sb[0]; bidx = si[0];
    for (int i = 1; i < 4; i++) {
        float vv = sb[i]; int ii = si[i];
        if (vv < best || (vv == best && ii < bidx)) { best = vv; bidx = ii; }
    }

    int ind = min(bidx, N_E - 1);
    int kk = 0;                              /* coe = kk * PERS */
    size_t ibase = (size_t)b * TT;

    const float* eb = e + (size_t)b * TT * NPAD;
    const float QS = 1.0f / PERS;            /* 10240 */

    int q_0, q_1, q_2, q_3, q_4, q_5, q_6, q_7;

    /* drain phase-A VMEM so the vmcnt ledger starts at 0 */
    asm volatile("s_waitcnt vmcnt(0)" ::: "memory");
    __builtin_amdgcn_sched_barrier(0);

    int base0 = ind < 960 ? ind : 960;
    int b0 = base0, b1 = base0, b2 = base0, b3 = base0, b4 = base0;

    /* prologue: [8 loads + 1 volatile store] x 5 chunks (rows 1..40) */
    #pragma unroll
    for (int k = 0; k < DEP; k++) {
        const float* pE = eb + base0 + lane;
        int ti = 1 + k * GCH;
        ISSUE8
        if (lane == 0) *(volatile int*)(wind + ibase) = ind;
        __builtin_amdgcn_sched_barrier(0);
    }
    asm volatile("s_waitcnt vmcnt(37)" ::: "memory");  /* chunk 0 landed */
    __builtin_amdgcn_sched_barrier(0);
    {   /* q for chunk 0 (rows 1..8) */
        int tq = 1;
        bool _capn = (b0 + lane == 1023);
        QCOMP8
    }
    __builtin_amdgcn_sched_barrier(0);

    int t = 1;
    #pragma unroll 1
    for (int c = 0; c < 128; c++) {
        int cbI = ind < 960 ? ind : 960;     /* base for chunk c+5 */
        {   const float* pE = eb + cbI + lane;
            int ti = t + DEP * GCH;
            ISSUE8
        }
        __builtin_amdgcn_sched_barrier(0);

        int packed = 0;
        CHAIN8                                /* chunk c, base b0 */
        __builtin_amdgcn_sched_barrier(0);

        asm volatile("s_waitcnt vmcnt(36)" ::: "memory");  /* chunk c+1 landed */
        __builtin_amdgcn_sched_barrier(0);

        {   /* q for chunk c+1 (rows t+8..t+15), base b1 */
            int tq = t + GCH;
            bool _capn = (b1 + lane == 1023);
            QCOMP8
        }
        if (lane < GCH && t + lane < 1024) wind[ibase + t + lane] = packed;
        __builtin_amdgcn_sched_barrier(0);

        b0 = b1; b1 = b2; b2 = b3; b3 = b4; b4 = cbI;
        t += GCH;
    }
}

/* ---------------- K3: per-row hinge-loss partial + z_q gather + idx emit ------ */
__global__ __launch_bounds__(256) void k3_loss_zq(const float* __restrict__ e,
                                                  const int* __restrict__ wind,
                                                  const float* __restrict__ book,
                                                  float* __restrict__ part,
                                                  float* __restrict__ out) {
    int rIdx = blockIdx.x, tid = threadIdx.x;
    int ind = wind[rIdx];
    const float* er = e + (size_t)rIdx * NPAD;
    float eind = er[ind];
    float p = 0.0f;
    for (int n = tid; n < NCOL; n += 256) {
        float v = eind - er[n] + EPSC;
        p += v > 0.0f ? v : 0.0f;
    }
    __shared__ float sd[256];
    sd[tid] = p; __syncthreads();
    for (int s = 128; s > 0; s >>= 1) { if (tid < s) sd[tid] += sd[tid + s]; __syncthreads(); }
    if (tid == 0) { part[rIdx] = sd[0]; out[OUT_IDX + rIdx] = (float)ind; }
    out[(size_t)rIdx * 256 + tid] = book[(size_t)ind * EDIM + tid];   /* z_q */
}

/* ---------------- K4: final loss reduce + v ---------------- */
__global__ __launch_bounds__(256) void k4_final(const float* __restrict__ part,
                                                const int* __restrict__ wind,
                                                float* __restrict__ out) {
    int tid = threadIdx.x;
    float s = 0.0f;
    for (int i = tid; i < NROW; i += 256) s += part[i];
    __shared__ float sd[256];
    sd[tid] = s; __syncthreads();
    for (int st = 128; st > 0; st >>= 1) { if (tid < st) sd[tid] += sd[tid + st]; __syncthreads(); }
    if (tid == 0) {
        int mn = wind[0], mx = wind[TT - 1];
        for (int b = 1; b < BB; b++) {
            mn = min(mn, wind[(size_t)b * TT]);
            mx = max(mx, wind[(size_t)b * TT + TT - 1]);
        }
        out[OUT_LOSS] = 1.25f * sd[0] / ((float)NROW * (float)NCOL);
        out[OUT_V] = (float)(mx - mn);
    }
}

extern "C" void kernel_launch(void* const* d_in, const int* in_sizes, int n_in,
                              void* d_out, int out_size, void* d_ws, size_t ws_size,
                              hipStream_t stream) {
    const float* z    = (const float*)d_in[0];
    const float* book = (const float*)d_in[1];
    char* ws = (char*)d_ws;
    unsigned short* zb = (unsigned short*)(ws + WS_ZB);
    unsigned short* bb = (unsigned short*)(ws + WS_BBF);
    float* bsq  = (float*)(ws + WS_BSQ);
    float* e    = (float*)(ws + WS_E);
    int*   wind = (int*)(ws + WS_IND);
    float* part = (float*)(ws + WS_PART);
    float* out  = (float*)d_out;

    hipLaunchKernelGGL(k0_prep,    dim3(4096 + 1152), dim3(256), 0, stream, z, book, zb, bb, bsq);
    hipLaunchKernelGGL(k1_gemm,    dim3(128, 9),      dim3(256), 0, stream, zb, bb, bsq, e);
    hipLaunchKernelGGL(k2_scan,    dim3(16),          dim3(256), 0, stream, z, book, bsq, e, wind);
    hipLaunchKernelGGL(k3_loss_zq, dim3(16384),       dim3(256), 0, stream, e, wind, book, part, out);
    hipLaunchKernelGGL(k4_final,   dim3(1),           dim3(256), 0, stream, part, wind, out);
}

// Round 8
// 241.000 us; speedup vs baseline: 1.1339x; 1.1339x over previous
//
#include <hip/hip_runtime.h>

#define N_E   1024
#define EDIM  256
#define BB    16
#define TT    1024
#define NROW  (BB*TT)        /* 16384 */
#define NCOL  1025
#define NPAD  1152           /* 9*128 */
#define PERS  (0.1f/1024.0f)
#define EPSC  (1e-6f/1024.0f)

/* d_out layout (float32): z_q [0,4194304) | loss 4194304 | ind [4194305,+16384) | v 4210689 */
#define OUT_LOSS 4194304
#define OUT_IDX  4194305
#define OUT_V    4210689

/* ws layout (bytes) */
#define WS_ZB   0ull                               /* 16384*256*2  = 8388608  */
#define WS_BBF  8388608ull                         /* 1152*256*2   = 589824   */
#define WS_BSQ  8978432ull                         /* 1152*4       = 4608     */
#define WS_E    8983552ull                         /* 16384*1152*4 = 75497472 */
#define WS_IND  84481024ull                        /* 16384*4                 */
#define WS_PART 84546560ull                        /* 16384*4                 */

typedef __attribute__((ext_vector_type(8))) short short8;
typedef __attribute__((ext_vector_type(4))) float floatx4;

__device__ __forceinline__ unsigned short f2bf(float f) {
    unsigned int u = __float_as_uint(f);
    u = (u + 0x7fffu + ((u >> 16) & 1u)) >> 16;   /* RNE */
    return (unsigned short)u;
}

/* Early-issued plain VMEM load; asm volatile pins issue order and result
   liveness. Lessons so far: (r0/r3) arrays or >~45 live prefetch regs get
   lowered to scratch -> serialized; (r2/r7) global_load_lds from one wave
   drains ~serially at ANY depth -> 117us both times. Plain VMEM loads into
   ~15 NAMED regs (r6) is the proven substrate; this round deepens it. */
__device__ __forceinline__ float gload_f32(const float* p) {
    float r;
    asm volatile("global_load_dword %0, %1, off" : "=v"(r) : "v"(p));
    return r;
}

/* ---------------- K0: convert z/book -> bf16, compute bsq (fp32) ---------------- */
__global__ __launch_bounds__(256) void k0_prep(const float* __restrict__ z,
                                               const float* __restrict__ book,
                                               unsigned short* __restrict__ zb,
                                               unsigned short* __restrict__ bb,
                                               float* __restrict__ bsq) {
    int bx = blockIdx.x, tid = threadIdx.x;
    if (bx < 4096) {                     /* z: 4096 blocks * 256 thr * 4 floats */
        float4 v = ((const float4*)z)[bx * 256 + tid];
        size_t o = ((size_t)bx * 256 + tid) * 4;
        zb[o + 0] = f2bf(v.x); zb[o + 1] = f2bf(v.y);
        zb[o + 2] = f2bf(v.z); zb[o + 3] = f2bf(v.w);
    } else {                             /* book rows, padded to 1152 with zeros */
        int row = bx - 4096;             /* 0..1151 */
        float v = (row < NCOL) ? book[(size_t)row * EDIM + tid] : 0.0f;
        bb[(size_t)row * EDIM + tid] = f2bf(v);
        __shared__ float sd[256];
        sd[tid] = v * v;
        __syncthreads();
        for (int s = 128; s > 0; s >>= 1) { if (tid < s) sd[tid] += sd[tid + s]; __syncthreads(); }
        if (tid == 0) bsq[row] = sd[0];
    }
}

/* ---------------- K1: e[r][n] = bsq[n] - 2 * dot(z[r], book[n])  (bf16 MFMA) ---- */
__global__ __launch_bounds__(256) void k1_gemm(const unsigned short* __restrict__ zb,
                                               const unsigned short* __restrict__ bb,
                                               const float* __restrict__ bsq,
                                               float* __restrict__ e) {
    int tid = threadIdx.x;
    int lane = tid & 63, w = tid >> 6;
    int mBase = blockIdx.x * 128 + (w >> 1) * 64;
    int nBase = blockIdx.y * 128 + (w & 1) * 64;
    int r = lane & 15, q = lane >> 4;

    floatx4 acc[4][4];
    #pragma unroll
    for (int i = 0; i < 4; i++)
        #pragma unroll
        for (int j = 0; j < 4; j++) acc[i][j] = (floatx4){0.f, 0.f, 0.f, 0.f};

    const short8* A = (const short8*)zb;   /* row stride 256 bf16 = 32 short8 */
    const short8* Bm = (const short8*)bb;

    #pragma unroll
    for (int ks = 0; ks < 8; ks++) {
        int k8 = ks * 4 + q;               /* short8 index in row: (ks*32+q*8)/8 */
        short8 a[4], b[4];
        #pragma unroll
        for (int i = 0; i < 4; i++) a[i] = A[(size_t)(mBase + i * 16 + r) * 32 + k8];
        #pragma unroll
        for (int j = 0; j < 4; j++) b[j] = Bm[(size_t)(nBase + j * 16 + r) * 32 + k8];
        #pragma unroll
        for (int i = 0; i < 4; i++)
            #pragma unroll
            for (int j = 0; j < 4; j++)
                acc[i][j] = __builtin_amdgcn_mfma_f32_16x16x32_bf16(a[i], b[j], acc[i][j], 0, 0, 0);
    }

    float bsql[4];
    #pragma unroll
    for (int j = 0; j < 4; j++) bsql[j] = bsq[nBase + j * 16 + r];

    #pragma unroll
    for (int i = 0; i < 4; i++)
        #pragma unroll
        for (int rr = 0; rr < 4; rr++) {
            int m = mBase + i * 16 + q * 4 + rr;
            float* erow = e + (size_t)m * NPAD;
            #pragma unroll
            for (int j = 0; j < 4; j++)
                erow[nBase + j * 16 + r] = fmaf(-2.0f, acc[i][j][rr], bsql[j]);
        }
}

/* ---------------- K2: serial neighbor scan, one block per batch row ------------
   Phase A (4 waves): fp32 argmin of d[b,0,:] reference-style.
   Phase B (wave 0): integer-scan, depth-4 pipeline, 6-row chunks.
   32-col window, 2 rows packed per 64-lane load (lane = (row&1)*32 + col):
   chunk = 6 rows -> 3 loads. 4 chunks in flight -> issue-to-wait cover
   ~3 iterations (~1400 cy) >= e-fetch latency. Live prefetch regs:
   4 sets x 3 A + 3 q = 15 named scalars (r6-proven no-spill shape).
   Drift bound: snapshot at iter c serves chunk c+4; rows between snapshot
   and last row of that chunk = 4*6+5 = 29 <= 30 usable cols. Base clamp
   min(ind,992): when base=992, rel <= 31 and col 1023 is the cap lane
   (q forced 0 = exact reference behavior at ind=1023); lane31's shfl-B
   garbage is only consumed at rel=31 = cap lane.
   vmcnt ledger: per iter [3 loads][chain][1 store][vmcnt(13)][qcomp].
   At the wait, ops newer than chunk c+1's loads: s(c-3) + (L+s)(c-2)
   + (L+s)(c-1) + L(c)+s(c) = 1+4+4+4 = 13 -> vmcnt(13) retires exactly
   chunk c+1 + one old store. Prologue [L x3 + volatile store] x4 = 16 ops,
   vmcnt(13) retires chunk 0. Stores provably issue every iter <= 170
   (lane 0: t <= 1021 < 1024); iter 171 is a guarded tail whose qcomp
   output is never consumed. Max outstanding 17 <= 63.                      */

#define GCH 6

#define DECLW float A0_0, A0_1, A0_2, A1_0, A1_1, A1_2, \
                    A2_0, A2_1, A2_2, A3_0, A3_1, A3_2; \
              int q_0, q_1, q_2;

#define LDOP(S,k) { int _t = ti + 2*k + _g; _t = _t < 1024 ? _t : 1023; \
                    A##S##_##k = gload_f32(_pe + (size_t)_t * NPAD); }
#define LDSET0 LDOP(0,0) LDOP(0,1) LDOP(0,2)
#define LDSET1 LDOP(1,0) LDOP(1,1) LDOP(1,2)
#define LDSET2 LDOP(2,0) LDOP(2,1) LDOP(2,2)
#define LDSET3 LDOP(3,0) LDOP(3,1) LDOP(3,2)

#define QCOP(S,k) { float _bv = __shfl_down(A##S##_##k, 1, 32); \
                    int _qv = (int)((_bv - A##S##_##k) * QS); \
                    q_##k = _capn ? 0 : _qv; }
#define QCSET0 QCOP(0,0) QCOP(0,1) QCOP(0,2)
#define QCSET1 QCOP(1,0) QCOP(1,1) QCOP(1,2)
#define QCSET2 QCOP(2,0) QCOP(2,1) QCOP(2,2)
#define QCSET3 QCOP(3,0) QCOP(3,1) QCOP(3,2)

/* chain step: row j of chunk, q register k=j>>1, lane offset h=(j&1)*32 */
#define CHS(j,k,h) { int _rel = ind - b0; \
                     int _qv = __builtin_amdgcn_readlane(q_##k, _rel + h); \
                     bool _stay = (kk <= _qv); \
                     int _ip1 = ind + 1; _ip1 = _ip1 < 1023 ? _ip1 : 1023; \
                     ind = _stay ? ind : _ip1; \
                     kk  = _stay ? kk + 1 : 0; \
                     packed = (lane == j) ? ind : packed; }
#define CHAIN6 CHS(0,0,0) CHS(1,0,32) CHS(2,1,0) CHS(3,1,32) CHS(4,2,0) CHS(5,2,32)

/* iter c: issue chunk c+4 into set SI=c%4; chain chunk c (base b0);
   wait; q-compute chunk c+1 from set SQ=(c+1)%4 (cap base b1). */
#define ITERX(SI, SQ) { \
    int cbI = ind < 992 ? ind : 992;                 /* base, chunk c+4 */ \
    { const float* _pe = eb + cbI + _cl; int ti = t + 24; LDSET##SI } \
    __builtin_amdgcn_sched_barrier(0); \
    int packed = 0; \
    CHAIN6 \
    if (lane < GCH && t + lane < 1024) wind[ibase + t + lane] = packed; \
    __builtin_amdgcn_sched_barrier(0); \
    asm volatile("s_waitcnt vmcnt(13)" ::: "memory"); /* chunk c+1 landed */ \
    __builtin_amdgcn_sched_barrier(0); \
    { bool _capn = (b1 + _cl == 1023); QCSET##SQ } \
    __builtin_amdgcn_sched_barrier(0); \
    b0 = b1; b1 = b2; b2 = b3; b3 = cbI; \
    t += GCH; }

__global__ __launch_bounds__(256, 1) void k2_scan(const float* __restrict__ z,
                                                  const float* __restrict__ book,
                                                  const float* __restrict__ bsq,
                                                  const float* __restrict__ e,
                                                  int* __restrict__ wind) {
    __shared__ float sb[4]; __shared__ int si[4];

    int b = blockIdx.x, tid = threadIdx.x;
    int lane = tid & 63, w = tid >> 6;

    const float4* zr = (const float4*)(z + (size_t)b * TT * EDIM);  /* t=0 row */
    float4 zv = zr[lane];
    float s = zv.x * zv.x + zv.y * zv.y + zv.z * zv.z + zv.w * zv.w;
    #pragma unroll
    for (int off = 32; off; off >>= 1) s += __shfl_xor(s, off, 64);
    float zsq = s;

    float best = 3.4e38f; int bidx = 0;
    for (int wi = w; wi < 17; wi += 4) {
        int n = wi * 64 + lane;
        if (n < NCOL) {
            const float4* br = (const float4*)(book + (size_t)n * EDIM);
            float c0 = 0.f, c1 = 0.f, c2 = 0.f, c3 = 0.f;
            #pragma unroll 8
            for (int k = 0; k < 64; k++) {
                float4 bo = br[k]; float4 za = zr[k];
                c0 = fmaf(za.x, bo.x, c0); c1 = fmaf(za.y, bo.y, c1);
                c2 = fmaf(za.z, bo.z, c2); c3 = fmaf(za.w, bo.w, c3);
            }
            float cr = (c0 + c1) + (c2 + c3);
            float d0 = (zsq + bsq[n]) - 2.0f * cr;     /* reference-style formation */
            if (d0 < best || (d0 == best && n < bidx)) { best = d0; bidx = n; }
        }
    }
    #pragma unroll
    for (int off = 32; off; off >>= 1) {
        float ob = __shfl_xor(best, off, 64);
        int   oi = __shfl_xor(bidx, off, 64);
        if (ob < best || (ob == best && oi < bidx)) { best = ob; bidx = oi; }
    }
    if (lane == 0) { sb[w] = best; si[w] = bidx; }
    __syncthreads();
    if (w != 0) return;

    best = sb[0]; bidx = si[0];
    for (int i = 1; i < 4; i++) {
        float vv = sb[i]; int ii = si[i];
        if (vv < best || (vv == best && ii < bidx)) { best = vv; bidx = ii; }
    }

    int ind = min(bidx, N_E - 1);
    int kk = 0;                              /* coe = kk * PERS */
    size_t ibase = (size_t)b * TT;

    const float* eb = e + (size_t)b * TT * NPAD;
    const float QS = 1.0f / PERS;            /* 10240 */

    int _g = lane >> 5;                      /* row-in-pair */
    int _cl = lane & 31;                     /* col-in-window */

    DECLW                                    /* A{0..3}_{0..2}, q_{0..2} */

    /* drain phase-A VMEM so the vmcnt ledger starts clean */
    asm volatile("s_waitcnt vmcnt(0)" ::: "memory");
    __builtin_amdgcn_sched_barrier(0);

    int base0 = ind < 992 ? ind : 992;
    int b0 = base0, b1 = base0, b2 = base0, b3 = base0;

    /* prologue: chunks 0..3 (rows 1-6, 7-12, 13-18, 19-24), each
       [3 loads + 1 volatile wind store] to establish the uniform ledger */
    { const float* _pe = eb + base0 + _cl; int ti = 1;  LDSET0 }
    if (lane == 0) *(volatile int*)(wind + ibase) = ind;
    { const float* _pe = eb + base0 + _cl; int ti = 7;  LDSET1 }
    if (lane == 0) *(volatile int*)(wind + ibase) = ind;
    { const float* _pe = eb + base0 + _cl; int ti = 13; LDSET2 }
    if (lane == 0) *(volatile int*)(wind + ibase) = ind;
    { const float* _pe = eb + base0 + _cl; int ti = 19; LDSET3 }
    if (lane == 0) *(volatile int*)(wind + ibase) = ind;
    __builtin_amdgcn_sched_barrier(0);
    asm volatile("s_waitcnt vmcnt(13)" ::: "memory");  /* chunk 0 landed */
    __builtin_amdgcn_sched_barrier(0);
    {   /* q for chunk 0 */
        bool _capn = (b0 + _cl == 1023);
        QCSET0
    }
    __builtin_amdgcn_sched_barrier(0);

    int t = 1;
    #pragma unroll 1
    for (int cc = 0; cc < 43; cc++) {        /* 172 iters; chunks 0..170 real */
        ITERX(0, 1)
        ITERX(1, 2)
        ITERX(2, 3)
        ITERX(3, 0)
    }
}

/* ---------------- K3: per-row hinge-loss partial + z_q gather + idx emit ------ */
__global__ __launch_bounds__(256) void k3_loss_zq(const float* __restrict__ e,
                                                  const int* __restrict__ wind,
                                                  const float* __restrict__ book,
                                                  float* __restrict__ part,
                                                  float* __restrict__ out) {
    int rIdx = blockIdx.x, tid = threadIdx.x;
    int ind = wind[rIdx];
    const float* er = e + (size_t)rIdx * NPAD;
    float eind = er[ind];
    float p = 0.0f;
    for (int n = tid; n < NCOL; n += 256) {
        float v = eind - er[n] + EPSC;
        p += v > 0.0f ? v : 0.0f;
    }
    __shared__ float sd[256];
    sd[tid] = p; __syncthreads();
    for (int s = 128; s > 0; s >>= 1) { if (tid < s) sd[tid] += sd[tid + s]; __syncthreads(); }
    if (tid == 0) { part[rIdx] = sd[0]; out[OUT_IDX + rIdx] = (float)ind; }
    out[(size_t)rIdx * 256 + tid] = book[(size_t)ind * EDIM + tid];   /* z_q */
}

/* ---------------- K4: final loss reduce + v ---------------- */
__global__ __launch_bounds__(256) void k4_final(const float* __restrict__ part,
                                                const int* __restrict__ wind,
                                                float* __restrict__ out) {
    int tid = threadIdx.x;
    float s = 0.0f;
    for (int i = tid; i < NROW; i += 256) s += part[i];
    __shared__ float sd[256];
    sd[tid] = s; __syncthreads();
    for (int st = 128; st > 0; st >>= 1) { if (tid < st) sd[tid] += sd[tid + st]; __syncthreads(); }
    if (tid == 0) {
        int mn = wind[0], mx = wind[TT - 1];
        for (int b = 1; b < BB; b++) {
            mn = min(mn, wind[(size_t)b * TT]);
            mx = max(mx, wind[(size_t)b * TT + TT - 1]);
        }
        out[OUT_LOSS] = 1.25f * sd[0] / ((float)NROW * (float)NCOL);
        out[OUT_V] = (float)(mx - mn);
    }
}

extern "C" void kernel_launch(void* const* d_in, const int* in_sizes, int n_in,
                              void* d_out, int out_size, void* d_ws, size_t ws_size,
                              hipStream_t stream) {
    const float* z    = (const float*)d_in[0];
    const float* book = (const float*)d_in[1];
    char* ws = (char*)d_ws;
    unsigned short* zb = (unsigned short*)(ws + WS_ZB);
    unsigned short* bb = (unsigned short*)(ws + WS_BBF);
    float* bsq  = (float*)(ws + WS_BSQ);
    float* e    = (float*)(ws + WS_E);
    int*   wind = (int*)(ws + WS_IND);
    float* part = (float*)(ws + WS_PART);
    float* out  = (float*)d_out;

    hipLaunchKernelGGL(k0_prep,    dim3(4096 + 1152), dim3(256), 0, stream, z, book, zb, bb, bsq);
    hipLaunchKernelGGL(k1_gemm,    dim3(128, 9),      dim3(256), 0, stream, zb, bb, bsq, e);
    hipLaunchKernelGGL(k2_scan,    dim3(16),          dim3(256), 0, stream, z, book, bsq, e, wind);
    hipLaunchKernelGGL(k3_loss_zq, dim3(16384),       dim3(256), 0, stream, e, wind, book, part, out);
    hipLaunchKernelGGL(k4_final,   dim3(1),           dim3(256), 0, stream, part, wind, out);
}